// Round 4
// baseline (239.609 us; speedup 1.0000x reference)
//
#include <hip/hip_runtime.h>

// ---------------- problem constants ----------------
#define B_     32
#define C_     2
#define L_     160000
#define HOP    512
#define PAD    1024
#define LPAD   162048            // L_ + 2*PAD
#define T_     313               // frames
#define BC     64                // B_*C_
#define M_     20032             // BC*T_
#define KCH    1025              // output channels per (real|imag)
#define N2     2050              // real+imag stacked
#define NP     2304              // N padded to 9*256
#define K_     2048
#define OUT_HALF 20532800UL      // M_*KCH
#define NKT    32                // K_/64 K-tiles
#define MT     79                // ceil(M_/256)
#define NT     9                 // NP/256
#define NWG    711               // MT*NT

typedef __attribute__((ext_vector_type(8))) short short8;
typedef __attribute__((ext_vector_type(16))) float f32x16;

static __device__ __forceinline__ short f2bf(float f) {
  union { float f; unsigned u; } v; v.f = f;
  unsigned u = v.u;
  unsigned r = (u + 0x7fffu + ((u >> 16) & 1u)) >> 16;  // RNE
  return (short)r;
}

// ---------------- prep: reflect-padded x as bf16 (vectorized) ----------------
__global__ void prep_xpad(const float* __restrict__ x, short* __restrict__ xpad) {
  int v = blockIdx.x * 256 + threadIdx.x;          // < 64 * 20256 = 1,296,384
  int bc = v / 20256;
  int p8 = (v - bc * 20256) * 8;
  const float* src = x + (size_t)bc * L_;
  int j0 = p8 - PAD;
  short8 o;
  if (j0 >= 0 && j0 + 7 < L_) {
    float4 a = *(const float4*)(src + j0);
    float4 b = *(const float4*)(src + j0 + 4);
    o[0]=f2bf(a.x); o[1]=f2bf(a.y); o[2]=f2bf(a.z); o[3]=f2bf(a.w);
    o[4]=f2bf(b.x); o[5]=f2bf(b.y); o[6]=f2bf(b.z); o[7]=f2bf(b.w);
  } else {
    #pragma unroll
    for (int r = 0; r < 8; ++r) {
      int j = j0 + r;
      j = j < 0 ? -j : j;
      j = j >= L_ ? 2 * L_ - 2 - j : j;
      o[r] = f2bf(src[j]);
    }
  }
  *(short8*)&xpad[(size_t)bc * LPAD + p8] = o;
}

// ---------------- prep: W_real || W_imag as bf16, padded to NP rows ----------------
__global__ void prep_wb(const float* __restrict__ wr, const float* __restrict__ wi,
                        short* __restrict__ wb) {
  int v = blockIdx.x * 256 + threadIdx.x;          // < 2304*256 = 589,824
  int n = v >> 8;
  int c8 = (v & 255) * 8;
  short8 o;
  const float* src = nullptr;
  if (n < KCH)      src = wr + (size_t)n * K_ + c8;
  else if (n < N2)  src = wi + (size_t)(n - KCH) * K_ + c8;
  if (src) {
    float4 a = *(const float4*)src;
    float4 b = *(const float4*)(src + 4);
    o[0]=f2bf(a.x); o[1]=f2bf(a.y); o[2]=f2bf(a.z); o[3]=f2bf(a.w);
    o[4]=f2bf(b.x); o[5]=f2bf(b.y); o[6]=f2bf(b.z); o[7]=f2bf(b.w);
  } else {
    o = (short8){0,0,0,0,0,0,0,0};
  }
  *(short8*)&wb[(size_t)n * K_ + c8] = o;
}

// ---------------- GEMM: 256x256 tile, BK=64, 32x32x16 MFMA, 2-buffer pipeline ----------------
#define GLOAD16(g, l) __builtin_amdgcn_global_load_lds(                        \
    (const __attribute__((address_space(1))) void*)(g),                        \
    (__attribute__((address_space(3))) void*)(l), 16, 0, 0)

__global__ __launch_bounds__(512, 2) void stft_gemm(const short* __restrict__ xpad,
                                                    const short* __restrict__ wb,
                                                    float* __restrict__ out) {
  // 2 buffers x (A[256][64] + B[256][64]) bf16 = 2 x 64 KB = 128 KB
  __shared__ short lds[65536];
  const int tid  = threadIdx.x;
  const int lane = tid & 63;
  const int wid  = tid >> 6;          // 0..7

  // ---- bijective XCD-chunked remap (T1, m204) ----
  const int id  = blockIdx.x;                  // 0..710
  const int xcd = id & 7, pos = id >> 3;       // q=88, r=7
  const int w   = (xcd < 7 ? xcd * 89 : 623) + pos;
  const int nt  = w / MT;
  const int mt  = w - nt * MT;
  const int M0 = mt * 256, N0 = nt * 256;

  // ---- staging setup: 4 A-loads + 4 B-loads per thread per K-tile ----
  // load j covers tile rows j*64 + (tid>>3); 8 chunks of 16B per 128B row.
  // LDS dest linear (tid*16); global source chunk inverse-swizzled (rule 21):
  // physical[row][cb] = logical[row][cb ^ ((row&7)<<4 bytes)]
  const int srow   = tid >> 3;                       // row within 64-row group
  const int schunk = (tid & 7) ^ (srow & 7);         // swizzled 16B chunk
  const short* aSrc[4];
  const short* bSrc[4];
  int ldsA[4], ldsB[4];
  #pragma unroll
  for (int j = 0; j < 4; ++j) {
    int row = j * 64 + srow;
    int m = M0 + row; if (m > M_ - 1) m = M_ - 1;    // clamp tail (not stored)
    int bc = m / T_;
    int t  = m - bc * T_;
    aSrc[j] = xpad + (size_t)bc * LPAD + (size_t)t * HOP + schunk * 8;
    int n = N0 + row;                                 // < 2304 always
    bSrc[j] = wb + (size_t)n * K_ + schunk * 8;
    ldsA[j] = j * 8192 + tid * 16;                    // bytes within A area
    ldsB[j] = 32768 + j * 8192 + tid * 16;            // bytes within B area
  }

  // ---- fragment read offsets (swizzled ds_read), 32x32x16 layout ----
  // operand lane map: row/col = lane&31, k = (lane>>5)*8 + j
  const int wr = wid >> 2, wc = wid & 3;   // 2M x 4N wave grid; per-wave 128x64
  const int l31 = lane & 31, kh = lane >> 5;
  int colx[4];                              // byte col per kstep, swizzled
  #pragma unroll
  for (int ks = 0; ks < 4; ++ks)
    colx[ks] = (ks * 32 + kh * 16) ^ ((lane & 7) << 4);
  int arow[4], brow[2];                     // row byte bases within buffer
  #pragma unroll
  for (int m = 0; m < 4; ++m) arow[m] = (wr * 128 + m * 32 + l31) * 128;
  #pragma unroll
  for (int n = 0; n < 2; ++n) brow[n] = 32768 + (wc * 64 + n * 32 + l31) * 128;

  f32x16 acc[4][2];
  #pragma unroll
  for (int m = 0; m < 4; ++m)
    #pragma unroll
    for (int n = 0; n < 2; ++n)
      #pragma unroll
      for (int r = 0; r < 16; ++r) acc[m][n][r] = 0.f;

  // ---- prologue: stage K-tile 0 into buffer 0 (8 loads in flight) ----
  {
    char* buf0 = (char*)lds;
    #pragma unroll
    for (int j = 0; j < 4; ++j) { GLOAD16(aSrc[j], buf0 + ldsA[j]); }
    #pragma unroll
    for (int j = 0; j < 4; ++j) { GLOAD16(bSrc[j], buf0 + ldsB[j]); }
  }

  // ---- main loop: one K-tile (BK=64) per iteration, 4 phases of 8 MFMA ----
  for (int kt = 0; kt < NKT; ++kt) {
    char* bufr = (char*)lds + (kt & 1) * 65536;
    char* bufw = (char*)lds + ((kt + 1) & 1) * 65536;
    const int kos = (kt + 1) * 64;
    const bool st = (kt < NKT - 1);

    // stage next tile's A BEFORE the wait -> counted vmcnt (never 0 till tail)
    if (st) {
      #pragma unroll
      for (int j = 0; j < 4; ++j) { GLOAD16(aSrc[j] + kos, bufw + ldsA[j]); }
      asm volatile("s_waitcnt vmcnt(4)" ::: "memory");
    } else {
      asm volatile("s_waitcnt vmcnt(0)" ::: "memory");
    }
    __builtin_amdgcn_s_barrier();   // tile kt fully landed for all waves

    #pragma unroll
    for (int ks = 0; ks < 4; ++ks) {
      if (ks == 1 && st) {          // stage next tile's B mid-iteration
        #pragma unroll
        for (int j = 0; j < 4; ++j) { GLOAD16(bSrc[j] + kos, bufw + ldsB[j]); }
      }
      short8 af[4], bf[2];
      #pragma unroll
      for (int m = 0; m < 4; ++m) af[m] = *(const short8*)(bufr + arow[m] + colx[ks]);
      #pragma unroll
      for (int n = 0; n < 2; ++n) bf[n] = *(const short8*)(bufr + brow[n] + colx[ks]);
      __builtin_amdgcn_s_barrier();
      __builtin_amdgcn_s_setprio(1);
      #pragma unroll
      for (int m = 0; m < 4; ++m)
        #pragma unroll
        for (int n = 0; n < 2; ++n)
          acc[m][n] = __builtin_amdgcn_mfma_f32_32x32x16_bf16(af[m], bf[n],
                                                              acc[m][n], 0, 0, 0);
      __builtin_amdgcn_s_setprio(0);
      __builtin_amdgcn_s_barrier();
    }
  }

  // ---- epilogue: 32x32 C/D layout col=lane&31, row=(reg&3)+8*(reg>>2)+4*(lane>>5) ----
  #pragma unroll
  for (int m = 0; m < 4; ++m) {
    #pragma unroll
    for (int n = 0; n < 2; ++n) {
      const int col  = N0 + wc * 64 + n * 32 + l31;
      const int rb0  = M0 + wr * 128 + m * 32 + kh * 4;
      #pragma unroll
      for (int reg = 0; reg < 16; ++reg) {
        int gm = rb0 + (reg & 3) + 8 * (reg >> 2);
        if (gm < M_) {
          float v = acc[m][n][reg];
          size_t rb = (size_t)gm * KCH;
          if (col < KCH)     out[rb + col] = v;                       // real
          else if (col < N2) out[OUT_HALF + rb + (col - KCH)] = v;    // imag
        }
      }
    }
  }
}

// ---------------- launcher ----------------
extern "C" void kernel_launch(void* const* d_in, const int* in_sizes, int n_in,
                              void* d_out, int out_size, void* d_ws, size_t ws_size,
                              hipStream_t stream) {
  const float* x  = (const float*)d_in[0];
  const float* Wr = (const float*)d_in[1];
  const float* Wi = (const float*)d_in[2];
  float* out = (float*)d_out;

  short* xpad = (short*)d_ws;                           // 10,371,072 bf16 = 20.7 MB
  short* wbuf = (short*)d_ws + (size_t)BC * LPAD;       //  4,718,592 bf16 =  9.4 MB

  prep_xpad<<<5064, 256, 0, stream>>>(x, xpad);         // 5064*256 = 1,296,384
  prep_wb<<<2304, 256, 0, stream>>>(Wr, Wi, wbuf);      // 2304*256 = 589,824

  stft_gemm<<<NWG, 512, 0, stream>>>(xpad, wbuf, out);
}

// Round 5
// 205.625 us; speedup vs baseline: 1.1653x; 1.1653x over previous
//
#include <hip/hip_runtime.h>

// ---------------- problem constants ----------------
#define B_     32
#define C_     2
#define L_     160000
#define HOP    512
#define PAD    1024
#define LPAD   162048            // L_ + 2*PAD
#define T_     313               // frames
#define BC     64                // B_*C_
#define M_     20032             // BC*T_
#define KCH    1025              // output channels per (real|imag)
#define OUT_HALF 20532800UL      // M_*KCH
#define PL     81024             // plane length per bc (LPAD/2)
#define KD     1024              // decimated K
#define ND     1024              // B rows (interleaved re/im)
#define NKT    32                // KD/32 K-tiles
#define MT     79                // ceil(M_/256)
#define NTD    8                 // ND/128
#define NWG    632               // MT*NTD

typedef __attribute__((ext_vector_type(8))) short short8;
typedef __attribute__((ext_vector_type(4))) float f32x4;

static __device__ __forceinline__ short f2bf(float f) {
  union { float f; unsigned u; } v; v.f = f;
  unsigned u = v.u;
  unsigned r = (u + 0x7fffu + ((u >> 16) & 1u)) >> 16;  // RNE
  return (short)r;
}

// ---------------- prep 1: even/odd deinterleaved reflect-padded planes ----------------
// plane_s[bc][p] = bf16( x[bc][ reflect(2p + s - 1024) ] ),  p in [0, 81024)
__global__ void prep_planes(const float* __restrict__ x,
                            short* __restrict__ pl0, short* __restrict__ pl1) {
  int v = blockIdx.x * 256 + threadIdx.x;           // < 64*10128 = 648192
  int bc = v / 10128;
  int r  = v - bc * 10128;
  int p0 = r * 8;                                   // 8 p-positions -> 16 samples
  const float* src = x + (size_t)bc * L_;
  short8 e, o;
  if (r >= 64 && r <= 10000) {                      // fully interior
    int j0 = 16 * r - 1024;
    #pragma unroll
    for (int qq = 0; qq < 4; ++qq) {
      float4 f = *(const float4*)(src + j0 + qq * 4);
      e[qq * 2 + 0] = f2bf(f.x); o[qq * 2 + 0] = f2bf(f.y);
      e[qq * 2 + 1] = f2bf(f.z); o[qq * 2 + 1] = f2bf(f.w);
    }
  } else {
    #pragma unroll
    for (int u = 0; u < 16; ++u) {
      int j = 16 * r + u - 1024;
      j = j < 0 ? -j : j;
      j = j >= L_ ? 2 * L_ - 2 - j : j;
      short b = f2bf(src[j]);
      if (u & 1) o[u >> 1] = b; else e[u >> 1] = b;
    }
  }
  *(short8*)&pl0[(size_t)bc * PL + p0] = e;
  *(short8*)&pl1[(size_t)bc * PL + p0] = o;
}

// ---------------- prep 2: windowed DFT-1024 weights, interleaved re/im rows ----------------
// row 2k'   : cos(2*pi*n1*k'/1024) * w[2*n1+s]            (k' = 0..511)
// row 2k'+1 : k'==0 ? cos(pi*n1)*w  (the re[512] row)
//                   : -sin(2*pi*n1*k'/1024) * w
__global__ void prep_wb(short* __restrict__ wb0, short* __restrict__ wb1) {
  int id = blockIdx.x * 256 + threadIdx.x;          // < 2*1024*128 = 262144
  int s   = id >> 17;
  int row = (id >> 7) & 1023;
  int n8  = (id & 127) * 8;
  int kp  = row >> 1, e = row & 1;
  short8 ov;
  #pragma unroll
  for (int u = 0; u < 8; ++u) {
    int n1 = n8 + u;
    float win = 0.5f - 0.5f * cosf((float)(2 * n1 + s) * 3.0679615757712823e-3f); // pi/1024
    float tw;
    if (e == 0)       tw = cosf((float)((n1 * kp) & 1023) * 6.1359231515425649e-3f); // 2pi/1024
    else if (kp == 0) tw = (n1 & 1) ? -1.0f : 1.0f;       // cos(pi*n1): re[512] row
    else              tw = -sinf((float)((n1 * kp) & 1023) * 6.1359231515425649e-3f);
    ov[u] = f2bf(win * tw);
  }
  short* wb = s ? wb1 : wb0;
  *(short8*)&wb[(size_t)row * KD + n8] = ov;
}

// ---------------- GEMM: 256x128 tile, dual-s acc, BK=32, counted-vmcnt ----------------
#define GLOAD16(g, l) __builtin_amdgcn_global_load_lds(                        \
    (const __attribute__((address_space(1))) void*)(g),                        \
    (__attribute__((address_space(3))) void*)(l), 16, 0, 0)

__global__ __launch_bounds__(512, 2) void stft_gemm(const short* __restrict__ pl0,
                                                    const short* __restrict__ pl1,
                                                    const short* __restrict__ wb0,
                                                    const short* __restrict__ wb1,
                                                    float* __restrict__ out) {
  // per buffer: A0[256][32] A1[256][32] (16KB ea) + B0[128][32] B1[128][32] (8KB ea) = 48KB
  __shared__ short lds[2 * 24576];
  const int tid  = threadIdx.x;
  const int lane = tid & 63;
  const int wid  = tid >> 6;          // 0..7

  const int nt = blockIdx.x & 7;      // same-nt blocks share an XCD -> B L2-resident
  const int mt = blockIdx.x >> 3;     // 0..78
  const int M0 = mt * 256, N0 = nt * 128;

  // ---- staging pointers ----
  // A_s instr j (j=0,1): covers rows j*128 + (l>>2); chunk (l&3) ^ ((l>>3)&3) of 8 els
  // B_s instr: rows l>>2; same chunk swizzle. LDS dest linear (l*16 bytes).
  const int chunkSwz = ((tid & 3) ^ ((tid >> 3) & 3)) * 8;   // element offset
  const short* aP[2][2];
  const short* bP[2];
  #pragma unroll
  for (int j = 0; j < 2; ++j) {
    int row = j * 128 + (tid >> 2);
    int m = M0 + row; if (m > M_ - 1) m = M_ - 1;            // clamp (not stored)
    int bc = m / T_;
    int t  = m - bc * T_;
    size_t base = (size_t)bc * PL + (size_t)t * 256 + chunkSwz;
    aP[0][j] = pl0 + base;
    aP[1][j] = pl1 + base;
  }
  {
    int row = tid >> 2;                                       // 0..127
    size_t base = (size_t)(N0 + row) * KD + chunkSwz;
    bP[0] = wb0 + base;
    bP[1] = wb1 + base;
  }
  const int dA0 = tid * 16;                 // bytes into A0 area
  const int dA1 = 16384 + tid * 16;
  const int dB0 = 32768 + tid * 16;
  const int dB1 = 40960 + tid * 16;

  // ---- fragment read offsets (round-2 proven conflict-free pattern) ----
  const int wr = wid >> 1, wc = wid & 1;    // 4m x 2n waves; per-wave 64x64
  const int fr = lane & 15;
  const int xorb = ((lane >> 4) * 16) ^ ((fr & 6) << 3);
  int afOff[2][4], bfOff[2][4];
  #pragma unroll
  for (int i = 0; i < 4; ++i) {
    afOff[0][i] = (wr * 64 + i * 16 + fr) * 64 + xorb;
    afOff[1][i] = 16384 + (wr * 64 + i * 16 + fr) * 64 + xorb;
    bfOff[0][i] = 32768 + (wc * 64 + i * 16 + fr) * 64 + xorb;
    bfOff[1][i] = 40960 + (wc * 64 + i * 16 + fr) * 64 + xorb;
  }

  f32x4 acc[2][4][4];
  #pragma unroll
  for (int s = 0; s < 2; ++s)
    #pragma unroll
    for (int i = 0; i < 4; ++i)
      #pragma unroll
      for (int j = 0; j < 4; ++j) acc[s][i][j] = (f32x4){0.f, 0.f, 0.f, 0.f};

  // ---- prologue: stage kt=0 in issue order [A0,A0,B0 | A1,A1,B1] ----
  {
    char* buf = (char*)lds;
    GLOAD16(aP[0][0], buf + dA0);
    GLOAD16(aP[0][1], buf + dA0 + 8192);
    GLOAD16(bP[0],    buf + dB0);
    GLOAD16(aP[1][0], buf + dA1);
    GLOAD16(aP[1][1], buf + dA1 + 8192);
    GLOAD16(bP[1],    buf + dB1);
  }

  // ---- main loop: 2 phases (s=0, s=1) per K-tile; vmcnt never drains till tail ----
  for (int kt = 0; kt < NKT; ++kt) {
    char* bufR = (char*)lds + (kt & 1) * 49152;
    char* bufW = (char*)lds + ((kt + 1) & 1) * 49152;
    const int kos = (kt + 1) * 32;
    const bool st = (kt < NKT - 1);

    // ---- phase s=0 ----
    asm volatile("s_waitcnt vmcnt(3)" ::: "memory");   // A0,B0(kt) landed
    __builtin_amdgcn_s_barrier();
    if (st) {                                          // stage A0,B0 of kt+1
      GLOAD16(aP[0][0] + kos, bufW + dA0);
      GLOAD16(aP[0][1] + kos, bufW + dA0 + 8192);
      GLOAD16(bP[0] + kos,    bufW + dB0);
    }
    short8 af0[4], bf0[4];
    #pragma unroll
    for (int i = 0; i < 4; ++i) af0[i] = *(const short8*)(bufR + afOff[0][i]);
    #pragma unroll
    for (int i = 0; i < 4; ++i) bf0[i] = *(const short8*)(bufR + bfOff[0][i]);
    __builtin_amdgcn_s_barrier();
    __builtin_amdgcn_s_setprio(1);
    #pragma unroll
    for (int i = 0; i < 4; ++i)
      #pragma unroll
      for (int j = 0; j < 4; ++j)
        acc[0][i][j] = __builtin_amdgcn_mfma_f32_16x16x32_bf16(af0[i], bf0[j],
                                                               acc[0][i][j], 0, 0, 0);
    __builtin_amdgcn_s_setprio(0);

    // ---- phase s=1 ----
    if (st) asm volatile("s_waitcnt vmcnt(3)" ::: "memory");  // A1,B1(kt) landed
    else    asm volatile("s_waitcnt vmcnt(0)" ::: "memory");
    __builtin_amdgcn_s_barrier();
    if (st) {                                          // stage A1,B1 of kt+1
      GLOAD16(aP[1][0] + kos, bufW + dA1);
      GLOAD16(aP[1][1] + kos, bufW + dA1 + 8192);
      GLOAD16(bP[1] + kos,    bufW + dB1);
    }
    short8 af1[4], bf1[4];
    #pragma unroll
    for (int i = 0; i < 4; ++i) af1[i] = *(const short8*)(bufR + afOff[1][i]);
    #pragma unroll
    for (int i = 0; i < 4; ++i) bf1[i] = *(const short8*)(bufR + bfOff[1][i]);
    __builtin_amdgcn_s_barrier();
    __builtin_amdgcn_s_setprio(1);
    #pragma unroll
    for (int i = 0; i < 4; ++i)
      #pragma unroll
      for (int j = 0; j < 4; ++j)
        acc[1][i][j] = __builtin_amdgcn_mfma_f32_16x16x32_bf16(af1[i], bf1[j],
                                                               acc[1][i][j], 0, 0, 0);
    __builtin_amdgcn_s_setprio(0);
  }

  // ---- epilogue: twiddle combine  X[k] = Y0[q] + e^{-i pi q/1024} Y1[q] ----
  // C layout: col = lane&15, row = (lane>>4)*4 + reg. col parity: even=re, odd=im.
  float* outI = out + OUT_HALF;
  #pragma unroll
  for (int j = 0; j < 4; ++j) {
    const int c = N0 + wc * 64 + j * 16 + fr;        // global B-row index 0..1023
    const int q = c >> 1;
    const float ang = (float)q * 3.0679615757712823e-3f;   // pi*q/1024
    const float tr = cosf(ang), sn = sinf(ang);            // t = (tr, -sn)
    #pragma unroll
    for (int i = 0; i < 4; ++i) {
      #pragma unroll
      for (int r = 0; r < 4; ++r) {
        float v0 = acc[0][i][j][r];
        float v1 = acc[1][i][j][r];
        float p0 = __shfl_xor(v0, 1);
        float p1 = __shfl_xor(v1, 1);
        int gm = M0 + wr * 64 + i * 16 + ((lane >> 4) << 2) + r;
        if (gm < M_) {
          size_t rb = (size_t)gm * KCH;
          if ((c & 1) == 0) {
            // even lane: re outputs. y0r=v0 y0i=p0 y1r=v1 y1i=p1
            float ur = tr * v1 + sn * p1;                  // Re(t*y1)
            out[rb + q]          = v0 + ur;                // X[q].re
            out[rb + (1024 - q)] = v0 - ur;                // X[1024-q].re (conj)
          } else if (c == 1) {
            // special slot: v0,v1 hold Y_s[512]  ->  X[512] = Y0[512] - i*Y1[512]
            out [rb + 512]  = v0;
            outI[rb + 512]  = -v1;
            outI[rb + 0]    = 0.f;
            outI[rb + 1024] = 0.f;
          } else {
            // odd lane: im outputs. y0i=v0 y0r=p0 y1i=v1 y1r=p1
            float ui = tr * v1 - sn * p1;                  // Im(t*y1)
            outI[rb + q]          = v0 + ui;               // X[q].im
            outI[rb + (1024 - q)] = -(v0 - ui);            // X[1024-q].im (conj)
          }
        }
      }
    }
  }
}

// ---------------- launcher ----------------
extern "C" void kernel_launch(void* const* d_in, const int* in_sizes, int n_in,
                              void* d_out, int out_size, void* d_ws, size_t ws_size,
                              hipStream_t stream) {
  const float* x = (const float*)d_in[0];
  float* out = (float*)d_out;

  short* pl0 = (short*)d_ws;                        // 64*81024 = 5,185,536 bf16
  short* pl1 = pl0 + (size_t)BC * PL;               // 5,185,536
  short* wb0 = pl1 + (size_t)BC * PL;               // 1024*1024
  short* wb1 = wb0 + (size_t)ND * KD;               // 1024*1024   (total 24.9 MB)

  prep_planes<<<2532, 256, 0, stream>>>(x, pl0, pl1);   // 2532*256 = 648192
  prep_wb<<<1024, 256, 0, stream>>>(wb0, wb1);          // 1024*256 = 262144

  stft_gemm<<<NWG, 512, 0, stream>>>(pl0, pl1, wb0, wb1, out);
}

// Round 6
// 159.904 us; speedup vs baseline: 1.4984x; 1.2859x over previous
//
#include <hip/hip_runtime.h>

// ---------------- problem constants ----------------
#define B_     32
#define C_     2
#define L_     160000
#define HOP    512
#define PAD    1024
#define LPAD   162048            // L_ + 2*PAD
#define T_     313               // frames
#define BC     64                // B_*C_
#define M_     20032             // BC*T_
#define KCH    1025              // output channels per (real|imag)
#define OUT_HALF 20532800UL      // M_*KCH
#define PL     81024             // plane length per bc (LPAD/2)
#define KD     1024              // decimated K
#define ND     1024              // B rows (interleaved re/im)
#define NKT    32                // KD/32 K-tiles
#define MT     157               // ceil(M_/128)
#define NTD    8                 // ND/128
#define NWG    1256              // MT*NTD
#define LIMW   8336              // lim word offset: 128*65+16

typedef __attribute__((ext_vector_type(8))) short short8;
typedef __attribute__((ext_vector_type(4))) float f32x4;

static __device__ __forceinline__ short f2bf(float f) {
  union { float f; unsigned u; } v; v.f = f;
  unsigned u = v.u;
  unsigned r = (u + 0x7fffu + ((u >> 16) & 1u)) >> 16;  // RNE
  return (short)r;
}

// ---------------- prep 1: even/odd deinterleaved reflect-padded planes ----------------
__global__ void prep_planes(const float* __restrict__ x,
                            short* __restrict__ pl0, short* __restrict__ pl1) {
  int v = blockIdx.x * 256 + threadIdx.x;           // < 64*10128 = 648192
  int bc = v / 10128;
  int r  = v - bc * 10128;
  int p0 = r * 8;                                   // 8 p-positions -> 16 samples
  const float* src = x + (size_t)bc * L_;
  short8 e, o;
  if (r >= 64 && r <= 10000) {                      // fully interior
    int j0 = 16 * r - 1024;
    #pragma unroll
    for (int qq = 0; qq < 4; ++qq) {
      float4 f = *(const float4*)(src + j0 + qq * 4);
      e[qq * 2 + 0] = f2bf(f.x); o[qq * 2 + 0] = f2bf(f.y);
      e[qq * 2 + 1] = f2bf(f.z); o[qq * 2 + 1] = f2bf(f.w);
    }
  } else {
    #pragma unroll
    for (int u = 0; u < 16; ++u) {
      int j = 16 * r + u - 1024;
      j = j < 0 ? -j : j;
      j = j >= L_ ? 2 * L_ - 2 - j : j;
      short b = f2bf(src[j]);
      if (u & 1) o[u >> 1] = b; else e[u >> 1] = b;
    }
  }
  *(short8*)&pl0[(size_t)bc * PL + p0] = e;
  *(short8*)&pl1[(size_t)bc * PL + p0] = o;
}

// ---------------- prep 2: windowed DFT-1024 weights, interleaved re/im rows ----------------
__global__ void prep_wb(short* __restrict__ wb0, short* __restrict__ wb1) {
  int id = blockIdx.x * 256 + threadIdx.x;          // < 2*1024*128 = 262144
  int s   = id >> 17;
  int row = (id >> 7) & 1023;
  int n8  = (id & 127) * 8;
  int kp  = row >> 1, e = row & 1;
  short8 ov;
  #pragma unroll
  for (int u = 0; u < 8; ++u) {
    int n1 = n8 + u;
    float win = 0.5f - 0.5f * cosf((float)(2 * n1 + s) * 3.0679615757712823e-3f); // pi/1024
    float tw;
    if (e == 0)       tw = cosf((float)((n1 * kp) & 1023) * 6.1359231515425649e-3f); // 2pi/1024
    else if (kp == 0) tw = (n1 & 1) ? -1.0f : 1.0f;       // cos(pi*n1): re[512] row
    else              tw = -sinf((float)((n1 * kp) & 1023) * 6.1359231515425649e-3f);
    ov[u] = f2bf(win * tw);
  }
  short* wb = s ? wb1 : wb0;
  *(short8*)&wb[(size_t)row * KD + n8] = ov;
}

// ---------------- GEMM: 128x128 tile, dual-s acc, BK=32, counted-vmcnt ----------------
#define GLOAD16(g, l) __builtin_amdgcn_global_load_lds(                        \
    (const __attribute__((address_space(1))) void*)(g),                        \
    (__attribute__((address_space(3))) void*)(l), 16, 0, 0)

__global__ __launch_bounds__(256, 2) void stft_gemm(const short* __restrict__ pl0,
                                                    const short* __restrict__ pl1,
                                                    const short* __restrict__ wb0,
                                                    const short* __restrict__ wb1,
                                                    float* __restrict__ out) {
  // main loop: 2 buffers x (A0,A1,B0,B1 each [128][32] = 8KB) = 64KB
  // epilogue reuse: lre[128][65] + pad + lim[128][65] fp32 = 66624 B
  __shared__ __align__(16) char lds[66688];
  const int tid  = threadIdx.x;
  const int lane = tid & 63;
  const int wid  = tid >> 6;          // 0..3

  const int nt = blockIdx.x & 7;      // same-nt blocks share an XCD -> B L2-resident
  const int mt = blockIdx.x >> 3;     // 0..156
  const int M0 = mt * 128, N0 = nt * 128;

  // ---- staging: per thread 2 loads per operand per s (rows j*64 + tid>>2) ----
  const int chunkSwz = ((tid & 3) ^ ((tid >> 3) & 3)) * 8;   // inverse-swizzled source
  const short* aP[2][2];
  const short* bP[2][2];
  #pragma unroll
  for (int j = 0; j < 2; ++j) {
    int row = j * 64 + (tid >> 2);
    int m = M0 + row; if (m > M_ - 1) m = M_ - 1;            // clamp (not stored)
    int bc = m / T_;
    int t  = m - bc * T_;
    size_t base = (size_t)bc * PL + (size_t)t * 256 + chunkSwz;
    aP[0][j] = pl0 + base;
    aP[1][j] = pl1 + base;
    size_t bb = (size_t)(N0 + row) * KD + chunkSwz;
    bP[0][j] = wb0 + bb;
    bP[1][j] = wb1 + bb;
  }
  // LDS dest byte offsets within buffer: A0:0  A1:8192  B0:16384  B1:24576
  const int dst[2] = { 0 * 4096 + tid * 16, 1 * 4096 + tid * 16 };

  // ---- fragment read offsets (proven conflict-free 64B-row XOR pattern) ----
  const int wr = wid >> 1, wc = wid & 1;    // 2m x 2n waves; per-wave 64x64
  const int fr = lane & 15;
  const int xorb = ((lane >> 4) * 16) ^ ((fr & 6) << 3);
  int afOff[2][4], bfOff[2][4];
  #pragma unroll
  for (int i = 0; i < 4; ++i) {
    afOff[0][i] = (wr * 64 + i * 16 + fr) * 64 + xorb;
    afOff[1][i] = 8192 + (wr * 64 + i * 16 + fr) * 64 + xorb;
    bfOff[0][i] = 16384 + (wc * 64 + i * 16 + fr) * 64 + xorb;
    bfOff[1][i] = 24576 + (wc * 64 + i * 16 + fr) * 64 + xorb;
  }

  f32x4 acc[2][4][4];
  #pragma unroll
  for (int s = 0; s < 2; ++s)
    #pragma unroll
    for (int i = 0; i < 4; ++i)
      #pragma unroll
      for (int j = 0; j < 4; ++j) acc[s][i][j] = (f32x4){0.f, 0.f, 0.f, 0.f};

  // ---- prologue: stage kt=0, group s0 then s1 (4 loads each) ----
  {
    char* buf = lds;
    GLOAD16(aP[0][0], buf + dst[0]);
    GLOAD16(aP[0][1], buf + dst[1]);
    GLOAD16(bP[0][0], buf + 16384 + dst[0]);
    GLOAD16(bP[0][1], buf + 16384 + dst[1]);
    GLOAD16(aP[1][0], buf + 8192 + dst[0]);
    GLOAD16(aP[1][1], buf + 8192 + dst[1]);
    GLOAD16(bP[1][0], buf + 24576 + dst[0]);
    GLOAD16(bP[1][1], buf + 24576 + dst[1]);
  }

  // ---- main loop: 2 phases (s=0,1) per K-tile; counted vmcnt(4) ----
  for (int kt = 0; kt < NKT; ++kt) {
    char* bufR = lds + (kt & 1) * 32768;
    char* bufW = lds + ((kt + 1) & 1) * 32768;
    const int kos = (kt + 1) * 32;
    const bool st = (kt < NKT - 1);

    // phase s=0
    asm volatile("s_waitcnt vmcnt(4)" ::: "memory");   // s0(kt) landed
    __builtin_amdgcn_s_barrier();
    if (st) {
      GLOAD16(aP[0][0] + kos, bufW + dst[0]);
      GLOAD16(aP[0][1] + kos, bufW + dst[1]);
      GLOAD16(bP[0][0] + kos, bufW + 16384 + dst[0]);
      GLOAD16(bP[0][1] + kos, bufW + 16384 + dst[1]);
    }
    short8 af0[4], bf0[4];
    #pragma unroll
    for (int i = 0; i < 4; ++i) af0[i] = *(const short8*)(bufR + afOff[0][i]);
    #pragma unroll
    for (int i = 0; i < 4; ++i) bf0[i] = *(const short8*)(bufR + bfOff[0][i]);
    __builtin_amdgcn_s_barrier();
    __builtin_amdgcn_s_setprio(1);
    #pragma unroll
    for (int i = 0; i < 4; ++i)
      #pragma unroll
      for (int j = 0; j < 4; ++j)
        acc[0][i][j] = __builtin_amdgcn_mfma_f32_16x16x32_bf16(af0[i], bf0[j],
                                                               acc[0][i][j], 0, 0, 0);
    __builtin_amdgcn_s_setprio(0);

    // phase s=1
    if (st) asm volatile("s_waitcnt vmcnt(4)" ::: "memory");  // s1(kt) landed
    else    asm volatile("s_waitcnt vmcnt(0)" ::: "memory");
    __builtin_amdgcn_s_barrier();
    if (st) {
      GLOAD16(aP[1][0] + kos, bufW + 8192 + dst[0]);
      GLOAD16(aP[1][1] + kos, bufW + 8192 + dst[1]);
      GLOAD16(bP[1][0] + kos, bufW + 24576 + dst[0]);
      GLOAD16(bP[1][1] + kos, bufW + 24576 + dst[1]);
    }
    short8 af1[4], bf1[4];
    #pragma unroll
    for (int i = 0; i < 4; ++i) af1[i] = *(const short8*)(bufR + afOff[1][i]);
    #pragma unroll
    for (int i = 0; i < 4; ++i) bf1[i] = *(const short8*)(bufR + bfOff[1][i]);
    __builtin_amdgcn_s_barrier();
    __builtin_amdgcn_s_setprio(1);
    #pragma unroll
    for (int i = 0; i < 4; ++i)
      #pragma unroll
      for (int j = 0; j < 4; ++j)
        acc[1][i][j] = __builtin_amdgcn_mfma_f32_16x16x32_bf16(af1[i], bf1[j],
                                                               acc[1][i][j], 0, 0, 0);
    __builtin_amdgcn_s_setprio(0);
  }

  // ---- epilogue: twiddle combine, LDS-staged coalesced writes, 2 passes ----
  float* L = (float*)lds;
  float* outI = out + OUT_HALF;
  const float PIQ = 3.0679615757712823e-3f;     // pi/1024
  const int rgrp = (lane >> 4) << 2;            // row sub-base from lane

  __syncthreads();   // all main-loop LDS reads complete before reuse

  #pragma unroll
  for (int pass = 0; pass < 2; ++pass) {
    // stage: lo pass stages X[q] at idx q; hi pass stages +/-X[1024-q] at idx 63-q
    #pragma unroll
    for (int j = 0; j < 4; ++j) {
      int c  = wc * 64 + j * 16 + fr;           // local col 0..127
      int q  = c >> 1;                          // local 0..63
      int qg = nt * 64 + q;
      float ang = (float)qg * PIQ;
      float tr = cosf(ang), sn = sinf(ang);
      bool odd  = c & 1;
      bool spec = (nt == 0) && (c == 1);        // the Y[512] special row
      float sgn = odd ? -sn : sn;
      int widx = (odd ? LIMW : 0) + (pass ? (63 - q) : q);
      #pragma unroll
      for (int i = 0; i < 4; ++i) {
        int row = wr * 64 + i * 16 + rgrp;
        #pragma unroll
        for (int r = 0; r < 4; ++r) {
          float v0 = acc[0][i][j][r];
          float v1 = acc[1][i][j][r];
          float p1 = __shfl_xor(v1, 1);
          float u  = tr * v1 + sgn * p1;
          float val;
          if (pass == 0) val = v0 + u;                       // X[q]
          else           val = odd ? -(v0 - u) : (v0 - u);   // X[1024-q] (conj im)
          if (spec) val = 0.f;                               // X[0]/X[1024] im = 0
          L[widx + (row + r) * 65] = val;
          if (spec && pass == 0) {
            int gm = M0 + row + r;
            if (gm < M_) {                                   // X[512] = Y0 - i*Y1
              out [(size_t)gm * KCH + 512] = v0;
              outI[(size_t)gm * KCH + 512] = -v1;
            }
          }
        }
      }
    }
    __syncthreads();
    // write: instr i2 -> one row, 64 consecutive floats per wave (256B runs)
    {
      int col0 = pass ? (1024 - nt * 64 - 63) : (nt * 64);
      #pragma unroll
      for (int i2 = 0; i2 < 32; ++i2) {
        int row = wid + i2 * 4;
        int gm  = M0 + row;
        if (gm < M_) {
          size_t rb = (size_t)gm * KCH + col0 + lane;
          out [rb] = L[row * 65 + lane];
          outI[rb] = L[LIMW + row * 65 + lane];
        }
      }
    }
    __syncthreads();   // arrays reused by next pass
  }
}

// ---------------- launcher ----------------
extern "C" void kernel_launch(void* const* d_in, const int* in_sizes, int n_in,
                              void* d_out, int out_size, void* d_ws, size_t ws_size,
                              hipStream_t stream) {
  const float* x = (const float*)d_in[0];
  float* out = (float*)d_out;

  short* pl0 = (short*)d_ws;                        // 64*81024 bf16
  short* pl1 = pl0 + (size_t)BC * PL;
  short* wb0 = pl1 + (size_t)BC * PL;               // 1024*1024
  short* wb1 = wb0 + (size_t)ND * KD;               // total 24.9 MB

  prep_planes<<<2532, 256, 0, stream>>>(x, pl0, pl1);
  prep_wb<<<1024, 256, 0, stream>>>(wb0, wb1);

  stft_gemm<<<NWG, 256, 0, stream>>>(pl0, pl1, wb0, wb1, out);
}

// Round 7
// 139.050 us; speedup vs baseline: 1.7232x; 1.1500x over previous
//
#include <hip/hip_runtime.h>

// ---------------- problem constants ----------------
#define B_     32
#define C_     2
#define L_     160000
#define HOP    512
#define PAD    1024
#define LPAD   162048            // L_ + 2*PAD
#define T_     313               // frames
#define BC     64                // B_*C_
#define M_     20032             // BC*T_
#define KCH    1025              // output channels per (real|imag)
#define OUT_HALF 20532800UL      // M_*KCH
#define PL     81024             // plane length per bc (LPAD/2)
#define KD     1024              // decimated K
#define ND     1024              // B rows (interleaved re/im)
#define NKT    32                // KD/32 K-tiles
#define MTP    160               // MT padded to 8*20 (157 real)
#define NWG    1280              // MTP*8
#define LIMW   8336              // im word offset: 128*65+16

typedef __attribute__((ext_vector_type(8))) short short8;
typedef __attribute__((ext_vector_type(4))) float f32x4;

static __device__ __forceinline__ short f2bf(float f) {
  union { float f; unsigned u; } v; v.f = f;
  unsigned u = v.u;
  unsigned r = (u + 0x7fffu + ((u >> 16) & 1u)) >> 16;  // RNE
  return (short)r;
}

// ---------------- prep 1: even/odd deinterleaved reflect-padded planes ----------------
__global__ void prep_planes(const float* __restrict__ x,
                            short* __restrict__ pl0, short* __restrict__ pl1) {
  int v = blockIdx.x * 256 + threadIdx.x;           // < 64*10128 = 648192
  int bc = v / 10128;
  int r  = v - bc * 10128;
  int p0 = r * 8;                                   // 8 p-positions -> 16 samples
  const float* src = x + (size_t)bc * L_;
  short8 e, o;
  if (r >= 64 && r <= 10000) {                      // fully interior
    int j0 = 16 * r - 1024;
    #pragma unroll
    for (int qq = 0; qq < 4; ++qq) {
      float4 f = *(const float4*)(src + j0 + qq * 4);
      e[qq * 2 + 0] = f2bf(f.x); o[qq * 2 + 0] = f2bf(f.y);
      e[qq * 2 + 1] = f2bf(f.z); o[qq * 2 + 1] = f2bf(f.w);
    }
  } else {
    #pragma unroll
    for (int u = 0; u < 16; ++u) {
      int j = 16 * r + u - 1024;
      j = j < 0 ? -j : j;
      j = j >= L_ ? 2 * L_ - 2 - j : j;
      short b = f2bf(src[j]);
      if (u & 1) o[u >> 1] = b; else e[u >> 1] = b;
    }
  }
  *(short8*)&pl0[(size_t)bc * PL + p0] = e;
  *(short8*)&pl1[(size_t)bc * PL + p0] = o;
}

// ---------------- prep 2: windowed DFT-1024 weights, interleaved re/im rows ----------------
__global__ void prep_wb(short* __restrict__ wb0, short* __restrict__ wb1) {
  int id = blockIdx.x * 256 + threadIdx.x;          // < 2*1024*128 = 262144
  int s   = id >> 17;
  int row = (id >> 7) & 1023;
  int n8  = (id & 127) * 8;
  int kp  = row >> 1, e = row & 1;
  short8 ov;
  #pragma unroll
  for (int u = 0; u < 8; ++u) {
    int n1 = n8 + u;
    float win = 0.5f - 0.5f * cosf((float)(2 * n1 + s) * 3.0679615757712823e-3f); // pi/1024
    float tw;
    if (e == 0)       tw = cosf((float)((n1 * kp) & 1023) * 6.1359231515425649e-3f); // 2pi/1024
    else if (kp == 0) tw = (n1 & 1) ? -1.0f : 1.0f;       // cos(pi*n1): re[512] row
    else              tw = -sinf((float)((n1 * kp) & 1023) * 6.1359231515425649e-3f);
    ov[u] = f2bf(win * tw);
  }
  short* wb = s ? wb1 : wb0;
  *(short8*)&wb[(size_t)row * KD + n8] = ov;
}

// ---------------- GEMM: 128x128 tile, 512 thr, dual-s acc, BK=32, counted-vmcnt ----------------
#define GLOAD16(g, l) __builtin_amdgcn_global_load_lds(                        \
    (const __attribute__((address_space(1))) void*)(g),                        \
    (__attribute__((address_space(3))) void*)(l), 16, 0, 0)

__global__ __launch_bounds__(512, 4) void stft_gemm(const short* __restrict__ pl0,
                                                    const short* __restrict__ pl1,
                                                    const short* __restrict__ wb0,
                                                    const short* __restrict__ wb1,
                                                    float* __restrict__ out) {
  // main loop: 2 buffers x (A0,A1,B0,B1 each [128][32] = 8KB) = 64KB
  // epilogue reuse: lre[128][65] + pad + lim[128][65] fp32 = 66624 B
  __shared__ __align__(16) char lds[66688];
  const int tid  = threadIdx.x;
  const int lane = tid & 63;
  const int wid  = tid >> 6;          // 0..7

  // ---- XCD remap: the 8 nt-blocks sharing an A-panel (same mt) are consecutive
  // ids with the SAME id%8 -> same XCD -> A fetched once per panel. B (4MB) is
  // L2-resident on every XCD.
  const int id = blockIdx.x;                   // 0..1279
  const int mt = (id & 7) * 20 + (id >> 6);    // 0..159 (>=157 are dead-padded)
  const int nt = (id >> 3) & 7;
  const int M0 = mt * 128, N0 = nt * 128;

  // ---- staging: 1 instr per operand per s; 512 threads cover [128][32] ----
  const int srow = tid >> 2;                                 // 0..127
  const int chunkSwz = ((tid & 3) ^ ((tid >> 3) & 3)) * 8;   // inverse-swizzled src
  const short* aP[2];
  const short* bP[2];
  {
    int m = M0 + srow; if (m > M_ - 1) m = M_ - 1;           // clamp (not stored)
    int bc = m / T_;
    int t  = m - bc * T_;
    size_t base = (size_t)bc * PL + (size_t)t * 256 + chunkSwz;
    aP[0] = pl0 + base;
    aP[1] = pl1 + base;
    size_t bb = (size_t)(N0 + srow) * KD + chunkSwz;
    bP[0] = wb0 + bb;
    bP[1] = wb1 + bb;
  }
  const int dstOff = tid * 16;   // linear LDS dest (per-wave base + lane*16)

  // ---- fragment read offsets (proven conflict-free 64B-row XOR pattern) ----
  const int wr = wid >> 2, wc = wid & 3;    // 2m x 4n waves; per-wave 64x32
  const int fr = lane & 15;
  const int xorb = ((lane >> 4) * 16) ^ ((fr & 6) << 3);
  int afOff[2][4], bfOff[2][2];
  #pragma unroll
  for (int s = 0; s < 2; ++s) {
    #pragma unroll
    for (int i = 0; i < 4; ++i)
      afOff[s][i] = s * 8192 + (wr * 64 + i * 16 + fr) * 64 + xorb;
    #pragma unroll
    for (int j = 0; j < 2; ++j)
      bfOff[s][j] = 16384 + s * 8192 + (wc * 32 + j * 16 + fr) * 64 + xorb;
  }

  f32x4 acc[2][4][2];
  #pragma unroll
  for (int s = 0; s < 2; ++s)
    #pragma unroll
    for (int i = 0; i < 4; ++i)
      #pragma unroll
      for (int j = 0; j < 2; ++j) acc[s][i][j] = (f32x4){0.f, 0.f, 0.f, 0.f};

  // ---- prologue: stage kt=0, s0 group then s1 group (2 loads each) ----
  GLOAD16(aP[0], lds + dstOff);
  GLOAD16(bP[0], lds + 16384 + dstOff);
  GLOAD16(aP[1], lds + 8192 + dstOff);
  GLOAD16(bP[1], lds + 24576 + dstOff);

  // ---- main loop: 2 phases (s=0,1) per K-tile; counted vmcnt(2) ----
  for (int kt = 0; kt < NKT; ++kt) {
    char* bufR = lds + (kt & 1) * 32768;
    char* bufW = lds + ((kt + 1) & 1) * 32768;
    const int kos = (kt + 1) * 32;
    const bool st = (kt < NKT - 1);

    // phase s=0
    asm volatile("s_waitcnt vmcnt(2)" ::: "memory");   // s0(kt) landed
    __builtin_amdgcn_s_barrier();
    if (st) {
      GLOAD16(aP[0] + kos, bufW + dstOff);
      GLOAD16(bP[0] + kos, bufW + 16384 + dstOff);
    }
    short8 af0[4], bf0[2];
    #pragma unroll
    for (int i = 0; i < 4; ++i) af0[i] = *(const short8*)(bufR + afOff[0][i]);
    #pragma unroll
    for (int j = 0; j < 2; ++j) bf0[j] = *(const short8*)(bufR + bfOff[0][j]);
    __builtin_amdgcn_s_barrier();
    __builtin_amdgcn_s_setprio(1);
    #pragma unroll
    for (int i = 0; i < 4; ++i)
      #pragma unroll
      for (int j = 0; j < 2; ++j)
        acc[0][i][j] = __builtin_amdgcn_mfma_f32_16x16x32_bf16(af0[i], bf0[j],
                                                               acc[0][i][j], 0, 0, 0);
    __builtin_amdgcn_s_setprio(0);

    // phase s=1
    if (st) asm volatile("s_waitcnt vmcnt(2)" ::: "memory");  // s1(kt) landed
    else    asm volatile("s_waitcnt vmcnt(0)" ::: "memory");
    __builtin_amdgcn_s_barrier();
    if (st) {
      GLOAD16(aP[1] + kos, bufW + 8192 + dstOff);
      GLOAD16(bP[1] + kos, bufW + 24576 + dstOff);
    }
    short8 af1[4], bf1[2];
    #pragma unroll
    for (int i = 0; i < 4; ++i) af1[i] = *(const short8*)(bufR + afOff[1][i]);
    #pragma unroll
    for (int j = 0; j < 2; ++j) bf1[j] = *(const short8*)(bufR + bfOff[1][j]);
    __builtin_amdgcn_s_barrier();
    __builtin_amdgcn_s_setprio(1);
    #pragma unroll
    for (int i = 0; i < 4; ++i)
      #pragma unroll
      for (int j = 0; j < 2; ++j)
        acc[1][i][j] = __builtin_amdgcn_mfma_f32_16x16x32_bf16(af1[i], bf1[j],
                                                               acc[1][i][j], 0, 0, 0);
    __builtin_amdgcn_s_setprio(0);
  }

  // ---- epilogue: twiddle combine, LDS-staged coalesced writes, 2 passes ----
  float* L = (float*)lds;
  float* outI = out + OUT_HALF;
  const float PIQ = 3.0679615757712823e-3f;     // pi/1024
  const int rgrp = (lane >> 4) << 2;            // row sub-base from lane

  __syncthreads();   // all main-loop LDS reads complete before reuse

  #pragma unroll
  for (int pass = 0; pass < 2; ++pass) {
    // stage: lo pass stages X[q] at idx q; hi pass stages +/-X[1024-q] at idx 63-q
    #pragma unroll
    for (int j = 0; j < 2; ++j) {
      int c  = wc * 32 + j * 16 + fr;           // local col 0..127
      int q  = c >> 1;                          // local 0..63
      int qg = nt * 64 + q;
      float ang = (float)qg * PIQ;
      float tr = cosf(ang), sn = sinf(ang);
      bool odd  = c & 1;
      bool spec = (nt == 0) && (c == 1);        // the Y[512] special row
      float sgn = odd ? -sn : sn;
      int widx = (odd ? LIMW : 0) + (pass ? (63 - q) : q);
      #pragma unroll
      for (int i = 0; i < 4; ++i) {
        int row = wr * 64 + i * 16 + rgrp;
        #pragma unroll
        for (int r = 0; r < 4; ++r) {
          float v0 = acc[0][i][j][r];
          float v1 = acc[1][i][j][r];
          float p1 = __shfl_xor(v1, 1);
          float u  = tr * v1 + sgn * p1;
          float val;
          if (pass == 0) val = v0 + u;                       // X[q]
          else           val = odd ? -(v0 - u) : (v0 - u);   // X[1024-q] (conj im)
          if (spec) val = 0.f;                               // X[0]/X[1024] im = 0
          L[widx + (row + r) * 65] = val;
          if (spec && pass == 0) {
            int gm = M0 + row + r;
            if (gm < M_) {                                   // X[512] = Y0 - i*Y1
              out [(size_t)gm * KCH + 512] = v0;
              outI[(size_t)gm * KCH + 512] = -v1;
            }
          }
        }
      }
    }
    __syncthreads();
    // write: each wave writes whole rows, 64 consecutive floats (256B runs)
    {
      int col0 = pass ? (1024 - nt * 64 - 63) : (nt * 64);
      #pragma unroll
      for (int i2 = 0; i2 < 16; ++i2) {
        int row = wid + i2 * 8;
        int gm  = M0 + row;
        if (gm < M_) {
          size_t rb = (size_t)gm * KCH + col0 + lane;
          out [rb] = L[row * 65 + lane];
          outI[rb] = L[LIMW + row * 65 + lane];
        }
      }
    }
    __syncthreads();   // arrays reused by next pass
  }
}

// ---------------- launcher ----------------
extern "C" void kernel_launch(void* const* d_in, const int* in_sizes, int n_in,
                              void* d_out, int out_size, void* d_ws, size_t ws_size,
                              hipStream_t stream) {
  const float* x = (const float*)d_in[0];
  float* out = (float*)d_out;

  short* pl0 = (short*)d_ws;                        // 64*81024 bf16
  short* pl1 = pl0 + (size_t)BC * PL;
  short* wb0 = pl1 + (size_t)BC * PL;               // 1024*1024
  short* wb1 = wb0 + (size_t)ND * KD;               // total 24.9 MB

  prep_planes<<<2532, 256, 0, stream>>>(x, pl0, pl1);
  prep_wb<<<1024, 256, 0, stream>>>(wb0, wb1);

  stft_gemm<<<NWG, 512, 0, stream>>>(pl0, pl1, wb0, wb1, out);
}